// Round 13
// baseline (39.940 us; speedup 1.0000x reference)
//
#include <hip/hip_runtime.h>

typedef __fp16 half2_t __attribute__((ext_vector_type(2)));
typedef float f32x4 __attribute__((ext_vector_type(4)));

#define S_DIM 4
#define F_DIM 4
#define E_DIM 65536
#define NCP   32

union H2U { unsigned u; half2_t h; };

// RNE f16 pack (v_cvt_f16_f32 is round-nearest-even)
__device__ __forceinline__ unsigned pkh(float a, float b) {
    H2U c; c.h.x = (__fp16)a; c.h.y = (__fp16)b;
    return c.u;
}
__device__ __forceinline__ half2_t ash2(unsigned u) {
    H2U c; c.u = u;
    return c.h;
}
__device__ __forceinline__ half2_t mkw(float a, float b) {
    half2_t h; h.x = (__fp16)a; h.y = (__fp16)b;
    return h;
}

// Cubic clamped-uniform basis + derivative (x3), rcp on the trans pipe.
// fs = float(span-3) in [0,28]; knots(i) = clamp((i-3)/29, 0, 1).
__device__ __forceinline__ void basis3(float u, float fs, float* N0, float* N1) {
    const float h = 1.0f / 29.0f;
    const float b = fs * h;
    const float L1 = u - b;
    const float L2 = u - fmaxf(b - h, 0.0f);
    const float L3 = u - fmaxf(b - 2.0f * h, 0.0f);
    const float R1 = (b + h) - u;
    const float R2 = fminf(b + 2.0f * h, 1.0f) - u;
    const float R3 = fminf(b + 3.0f * h, 1.0f) - u;
    const float i10 = __builtin_amdgcn_rcpf(R1 + L1);
    const float v01 = R1 * i10;
    const float v11 = L1 * i10;
    const float i20 = __builtin_amdgcn_rcpf(R1 + L2);
    float t = v01 * i20;
    const float v02 = R1 * t;
    float s = L2 * t;
    const float i21 = __builtin_amdgcn_rcpf(R2 + L1);
    t = v11 * i21;
    const float v12 = s + R2 * t;
    const float v22 = L1 * t;
    const float i30 = __builtin_amdgcn_rcpf(R1 + L3);
    t = v02 * i30;
    N0[0] = R1 * t;
    s = L3 * t;
    const float i31 = __builtin_amdgcn_rcpf(R2 + L2);
    t = v12 * i31;
    N0[1] = s + R2 * t;
    s = L2 * t;
    const float i32 = __builtin_amdgcn_rcpf(R3 + L1);
    t = v22 * i32;
    N0[2] = s + R3 * t;
    N0[3] = L1 * t;
    const float a0 = v02 * i30, a1 = v12 * i31, a2 = v22 * i32;
    N1[0] = -3.0f * a0;
    N1[1] = 3.0f * (a0 - a1);
    N1[2] = 3.0f * (a1 - a2);
    N1[3] = 3.0f * a2;
}

// Hot kernel: f16 LDS path only. Near-degenerate normals are queued to a
// fixup list in d_ws instead of being recomputed inline (frees ~20 VGPR ->
// 6 waves/SIMD at __launch_bounds__(256,6) without spills).
__global__ __launch_bounds__(256, 6) void nurbs_eval_kernel(
    const float* __restrict__ ep,   // (S,F,E,2)
    const float* __restrict__ cp,   // (S,F,NCP,NCP,3)
    float* __restrict__ out,        // points4 then normals4
    unsigned* __restrict__ wsc,     // [0]=count, [1..]=idx list
    unsigned cap)
{
    // E_c[u][v] = half2(c[u][v], c[u][v+1]); 3 comps, row stride 33 words.
    __shared__ unsigned sm[3 * 32 * 33];   // 12.4 KiB

    const int sf  = blockIdx.y;
    const int tid = threadIdx.x;

    // ---- Phase 0: uv load first (heads the critical chain), then cp staging loads ----
    const int e   = blockIdx.x * 256 + tid;
    const int idx = sf * E_DIM + e;
    const float2 uvp = ((const float2*)ep)[idx];

    const int su_ = tid >> 3, sm_ = tid & 7;
    const float* rowp = cp + ((size_t)sf * 1024 + (size_t)su_ * 32) * 3;
    const int o = 12 * sm_;
    const float4 Ld0 = *(const float4*)(rowp + o);
    const float4 Ld1 = *(const float4*)(rowp + o + 4);
    const float4 Ld2 = *(const float4*)(rowp + o + 8);
    // sm_==7: floats 96..99 would cross the row; they only feed unused E[u][31].
    const float4 Ld3 = *(const float4*)(rowp + ((sm_ == 7) ? 80 : (o + 12)));

    // ---- Phase A: basis evaluation (VALU + trans pipe) ----
    const float uu = uvp.x, vv = uvp.y;

    const float fsu = fminf(fmaxf(floorf(uu * 29.0f), 0.0f), 28.0f);
    const float fsv = fminf(fmaxf(floorf(vv * 29.0f), 0.0f), 28.0f);
    const int bu = (int)fsu, bv = (int)fsv;

    float bu0[4], bu1[4], bv0[4], bv1[4];
    basis3(uu, fsu, bu0, bu1);
    basis3(vv, fsv, bv0, bv1);

    const half2_t w00 = mkw(bv0[0], bv0[1]);
    const half2_t w01 = mkw(bv0[2], bv0[3]);
    const half2_t w10 = mkw(bv1[0], bv1[1]);
    const half2_t w11 = mkw(bv1[2], bv1[3]);

    // ---- Phase S: RNE pack + conflict-light LDS writes, one barrier ----
    {
        float f[16];
        f[0]=Ld0.x; f[1]=Ld0.y; f[2]=Ld0.z; f[3]=Ld0.w;
        f[4]=Ld1.x; f[5]=Ld1.y; f[6]=Ld1.z; f[7]=Ld1.w;
        f[8]=Ld2.x; f[9]=Ld2.y; f[10]=Ld2.z; f[11]=Ld2.w;
        f[12]=Ld3.x; f[13]=Ld3.y; f[14]=Ld3.z; f[15]=Ld3.w;
        unsigned* E0w = sm;
        unsigned* E1w = sm + 1056;
        unsigned* E2w = sm + 2112;
#pragma unroll
        for (int ee = 0; ee < 4; ++ee) {
            const int v = 4 * sm_ + ee;
            const int a = su_ * 33 + v;
            E0w[a] = pkh(f[3*ee+0], f[3*ee+3]);
            E1w[a] = pkh(f[3*ee+1], f[3*ee+4]);
            E2w[a] = pkh(f[3*ee+2], f[3*ee+5]);
        }
    }
    __syncthreads();

    const unsigned* E0 = sm;
    const unsigned* E1 = sm + 1056;
    const unsigned* E2 = sm + 2112;
    const int base = 33 * bu + bv;

    float px=0.f, py=0.f, pz=0.f;
    float dux=0.f, duy=0.f, duz=0.f;
    float dvx=0.f, dvy=0.f, dvz=0.f;

#pragma unroll
    for (int i = 0; i < 4; ++i) {
        const int a = base + 33 * i;
        const half2_t x0 = ash2(E0[a]), x1 = ash2(E0[a + 2]);
        const half2_t y0 = ash2(E1[a]), y1 = ash2(E1[a + 2]);
        const half2_t z0 = ash2(E2[a]), z1 = ash2(E2[a + 2]);
        const float t0x = __builtin_amdgcn_fdot2(x1, w01, __builtin_amdgcn_fdot2(x0, w00, 0.0f, false), false);
        const float t1x = __builtin_amdgcn_fdot2(x1, w11, __builtin_amdgcn_fdot2(x0, w10, 0.0f, false), false);
        const float t0y = __builtin_amdgcn_fdot2(y1, w01, __builtin_amdgcn_fdot2(y0, w00, 0.0f, false), false);
        const float t1y = __builtin_amdgcn_fdot2(y1, w11, __builtin_amdgcn_fdot2(y0, w10, 0.0f, false), false);
        const float t0z = __builtin_amdgcn_fdot2(z1, w01, __builtin_amdgcn_fdot2(z0, w00, 0.0f, false), false);
        const float t1z = __builtin_amdgcn_fdot2(z1, w11, __builtin_amdgcn_fdot2(z0, w10, 0.0f, false), false);
        px  = fmaf(bu0[i], t0x, px);  py  = fmaf(bu0[i], t0y, py);  pz  = fmaf(bu0[i], t0z, pz);
        dux = fmaf(bu1[i], t0x, dux); duy = fmaf(bu1[i], t0y, duy); duz = fmaf(bu1[i], t0z, duz);
        dvx = fmaf(bu0[i], t1x, dvx); dvy = fmaf(bu0[i], t1y, dvy); dvz = fmaf(bu0[i], t1z, dvz);
    }

    float nx = duy * dvz - duz * dvy;
    float ny = duz * dvx - dux * dvz;
    float nz = dux * dvy - duy * dvx;
    const float n2 = nx * nx + ny * ny + nz * nz;
    const float du2 = dux*dux + duy*duy + duz*duz;
    const float dv2 = dvx*dvx + dvy*dvy + dvz*dvz;

    // Near-parallel du,dv (~0.2% of points): queue for f32 fixup kernel.
    if (n2 < 4e-3f * (du2 * dv2)) {
        const unsigned pos = atomicAdd(wsc, 1u);
        if (pos < cap) wsc[1 + pos] = (unsigned)idx;
    }

    const float inv = __builtin_amdgcn_rsqf(fmaxf(n2, 1e-24f));
    nx *= inv; ny *= inv; nz *= inv;

    // Streamed outputs, never re-read: nontemporal to keep them out of L2.
    f32x4* outv = (f32x4*)out;
    f32x4 pt; pt[0]=px; pt[1]=py; pt[2]=pz; pt[3]=1.0f;
    f32x4 nm; nm[0]=nx; nm[1]=ny; nm[2]=nz; nm[3]=0.0f;
    __builtin_nontemporal_store(pt, &outv[idx]);
    __builtin_nontemporal_store(nm, &outv[(size_t)S_DIM * F_DIM * E_DIM + idx]);
}

// Fixup: recompute queued normals fully in f32 from global cp (L2-hot).
__global__ __launch_bounds__(256) void nurbs_fixup_kernel(
    const float* __restrict__ ep,
    const float* __restrict__ cp,
    float* __restrict__ out,
    const unsigned* __restrict__ wsc,
    unsigned cap)
{
    const unsigned count = min(wsc[0], cap);
    for (unsigned i = blockIdx.x * 256 + threadIdx.x; i < count; i += 16 * 256) {
        const int idx = (int)wsc[1 + i];
        const int sf = idx >> 16;                 // E_DIM == 65536
        const float2 uvp = ((const float2*)ep)[idx];
        const float uu = uvp.x, vv = uvp.y;
        const float fsu = fminf(fmaxf(floorf(uu * 29.0f), 0.0f), 28.0f);
        const float fsv = fminf(fmaxf(floorf(vv * 29.0f), 0.0f), 28.0f);
        const int bu = (int)fsu, bv = (int)fsv;
        float fu0[4], fu1[4], fv0[4], fv1[4];
        basis3(uu, fsu, fu0, fu1);
        basis3(vv, fsv, fv0, fv1);
        const float* patch = cp + (size_t)sf * 3072;
        float DUX=0.f, DUY=0.f, DUZ=0.f, DVX=0.f, DVY=0.f, DVZ=0.f;
#pragma unroll
        for (int r = 0; r < 4; ++r) {
            float s0x=0.f, s0y=0.f, s0z=0.f, s1x=0.f, s1y=0.f, s1z=0.f;
#pragma unroll
            for (int j = 0; j < 4; ++j) {
                const float* p = patch + (((bu + r) * 32) + (bv + j)) * 3;
                const float gx = p[0], gy = p[1], gz = p[2];
                s0x = fmaf(gx, fv0[j], s0x); s0y = fmaf(gy, fv0[j], s0y); s0z = fmaf(gz, fv0[j], s0z);
                s1x = fmaf(gx, fv1[j], s1x); s1y = fmaf(gy, fv1[j], s1y); s1z = fmaf(gz, fv1[j], s1z);
            }
            DUX = fmaf(fu1[r], s0x, DUX); DUY = fmaf(fu1[r], s0y, DUY); DUZ = fmaf(fu1[r], s0z, DUZ);
            DVX = fmaf(fu0[r], s1x, DVX); DVY = fmaf(fu0[r], s1y, DVY); DVZ = fmaf(fu0[r], s1z, DVZ);
        }
        float nx = DUY * DVZ - DUZ * DVY;
        float ny = DUZ * DVX - DUX * DVZ;
        float nz = DUX * DVY - DUY * DVX;
        const float n2 = nx * nx + ny * ny + nz * nz;
        const float inv = __builtin_amdgcn_rsqf(fmaxf(n2, 1e-24f));
        f32x4 nm; nm[0]=nx*inv; nm[1]=ny*inv; nm[2]=nz*inv; nm[3]=0.0f;
        ((f32x4*)out)[(size_t)S_DIM * F_DIM * E_DIM + idx] = nm;
    }
}

extern "C" void kernel_launch(void* const* d_in, const int* in_sizes, int n_in,
                              void* d_out, int out_size, void* d_ws, size_t ws_size,
                              hipStream_t stream) {
    const float* ep = (const float*)d_in[0];
    const float* cp = (const float*)d_in[1];
    float* out = (float*)d_out;
    unsigned* wsc = (unsigned*)d_ws;

    // wsc[0] = count, wsc[1..cap] = idx list. Overflow is safe: unfixed
    // points keep the f16 normal (absmax 0.043, still under threshold).
    unsigned cap = 0;
    if (ws_size >= 8) {
        size_t c = ws_size / 4 - 1;
        cap = (unsigned)(c > 1048576 ? 1048576 : c);
    }
    hipMemsetAsync(d_ws, 0, 4, stream);   // zero the count (capturable)

    dim3 grid(E_DIM / 256, S_DIM * F_DIM);
    dim3 block(256);
    hipLaunchKernelGGL(nurbs_eval_kernel, grid, block, 0, stream, ep, cp, out, wsc, cap);
    hipLaunchKernelGGL(nurbs_fixup_kernel, dim3(16), block, 0, stream, ep, cp, out, wsc, cap);
}

// Round 14
// 18.121 us; speedup vs baseline: 2.2041x; 2.2041x over previous
//
#include <hip/hip_runtime.h>

typedef __fp16 half2_t __attribute__((ext_vector_type(2)));
typedef float f32x4 __attribute__((ext_vector_type(4)));

#define S_DIM 4
#define F_DIM 4
#define E_DIM 65536
#define NCP   32

union H2U { unsigned u; half2_t h; };

// RNE f16 pack (v_cvt_f16_f32 is round-nearest-even; halves RTZ noise)
__device__ __forceinline__ unsigned pkh(float a, float b) {
    H2U c; c.h.x = (__fp16)a; c.h.y = (__fp16)b;
    return c.u;
}
__device__ __forceinline__ half2_t ash2(unsigned u) {
    H2U c; c.u = u;
    return c.h;
}
__device__ __forceinline__ half2_t mkw(float a, float b) {
    half2_t h; h.x = (__fp16)a; h.y = (__fp16)b;
    return h;
}

// Cubic clamped-uniform basis + derivative (x3), rcp on the trans pipe.
// fs = float(span-3) in [0,28]; knots(i) = clamp((i-3)/29, 0, 1).
__device__ __forceinline__ void basis3(float u, float fs, float* N0, float* N1) {
    const float h = 1.0f / 29.0f;
    const float b = fs * h;
    const float L1 = u - b;
    const float L2 = u - fmaxf(b - h, 0.0f);
    const float L3 = u - fmaxf(b - 2.0f * h, 0.0f);
    const float R1 = (b + h) - u;
    const float R2 = fminf(b + 2.0f * h, 1.0f) - u;
    const float R3 = fminf(b + 3.0f * h, 1.0f) - u;
    const float i10 = __builtin_amdgcn_rcpf(R1 + L1);
    const float v01 = R1 * i10;
    const float v11 = L1 * i10;
    const float i20 = __builtin_amdgcn_rcpf(R1 + L2);
    float t = v01 * i20;
    const float v02 = R1 * t;
    float s = L2 * t;
    const float i21 = __builtin_amdgcn_rcpf(R2 + L1);
    t = v11 * i21;
    const float v12 = s + R2 * t;
    const float v22 = L1 * t;
    const float i30 = __builtin_amdgcn_rcpf(R1 + L3);
    t = v02 * i30;
    N0[0] = R1 * t;
    s = L3 * t;
    const float i31 = __builtin_amdgcn_rcpf(R2 + L2);
    t = v12 * i31;
    N0[1] = s + R2 * t;
    s = L2 * t;
    const float i32 = __builtin_amdgcn_rcpf(R3 + L1);
    t = v22 * i32;
    N0[2] = s + R3 * t;
    N0[3] = L1 * t;
    const float a0 = v02 * i30, a1 = v12 * i31, a2 = v22 * i32;
    N1[0] = -3.0f * a0;
    N1[1] = 3.0f * (a0 - a1);
    N1[2] = 3.0f * (a1 - a2);
    N1[3] = 3.0f * a2;
}

__global__ __launch_bounds__(256) void nurbs_eval_kernel(
    const float* __restrict__ ep,   // (S,F,E,2)
    const float* __restrict__ cp,   // (S,F,NCP,NCP,3)
    float* __restrict__ out)        // points4 then normals4
{
    // E_c[u][v] = half2(c[u][v], c[u][v+1]); 3 comps, row stride 33 words.
    __shared__ unsigned sm[3 * 32 * 33];   // 12.4 KiB

    const int sf  = blockIdx.y;
    const int tid = threadIdx.x;

    // ---- Phase 0: uv load FIRST (heads the critical chain), then cp staging loads ----
    const int e   = blockIdx.x * 256 + tid;
    const int idx = sf * E_DIM + e;
    const float2 uvp = ((const float2*)ep)[idx];

    const int su_ = tid >> 3, sm_ = tid & 7;
    const float* rowp = cp + ((size_t)sf * 1024 + (size_t)su_ * 32) * 3;
    const int o = 12 * sm_;
    const float4 Ld0 = *(const float4*)(rowp + o);
    const float4 Ld1 = *(const float4*)(rowp + o + 4);
    const float4 Ld2 = *(const float4*)(rowp + o + 8);
    // sm_==7: floats 96..99 would cross the row; they only feed unused E[u][31].
    const float4 Ld3 = *(const float4*)(rowp + ((sm_ == 7) ? 80 : (o + 12)));

    // ---- Phase A: basis evaluation (pure VALU + trans) ----
    const float uu = uvp.x, vv = uvp.y;

    const float fsu = fminf(fmaxf(floorf(uu * 29.0f), 0.0f), 28.0f);
    const float fsv = fminf(fmaxf(floorf(vv * 29.0f), 0.0f), 28.0f);
    const int bu = (int)fsu, bv = (int)fsv;

    float bu0[4], bu1[4], bv0[4], bv1[4];
    basis3(uu, fsu, bu0, bu1);
    basis3(vv, fsv, bv0, bv1);

    const half2_t w00 = mkw(bv0[0], bv0[1]);
    const half2_t w01 = mkw(bv0[2], bv0[3]);
    const half2_t w10 = mkw(bv1[0], bv1[1]);
    const half2_t w11 = mkw(bv1[2], bv1[3]);

    // ---- Phase S: RNE pack + conflict-light LDS writes, one barrier ----
    {
        float f[16];
        f[0]=Ld0.x; f[1]=Ld0.y; f[2]=Ld0.z; f[3]=Ld0.w;
        f[4]=Ld1.x; f[5]=Ld1.y; f[6]=Ld1.z; f[7]=Ld1.w;
        f[8]=Ld2.x; f[9]=Ld2.y; f[10]=Ld2.z; f[11]=Ld2.w;
        f[12]=Ld3.x; f[13]=Ld3.y; f[14]=Ld3.z; f[15]=Ld3.w;
        unsigned* E0w = sm;
        unsigned* E1w = sm + 1056;
        unsigned* E2w = sm + 2112;
#pragma unroll
        for (int ee = 0; ee < 4; ++ee) {
            const int v = 4 * sm_ + ee;
            const int a = su_ * 33 + v;
            E0w[a] = pkh(f[3*ee+0], f[3*ee+3]);
            E1w[a] = pkh(f[3*ee+1], f[3*ee+4]);
            E2w[a] = pkh(f[3*ee+2], f[3*ee+5]);
        }
    }
    __syncthreads();

    const unsigned* E0 = sm;
    const unsigned* E1 = sm + 1056;
    const unsigned* E2 = sm + 2112;
    const int base = 33 * bu + bv;

    float px=0.f, py=0.f, pz=0.f;
    float dux=0.f, duy=0.f, duz=0.f;
    float dvx=0.f, dvy=0.f, dvz=0.f;

#pragma unroll
    for (int i = 0; i < 4; ++i) {
        const int a = base + 33 * i;
        const half2_t x0 = ash2(E0[a]), x1 = ash2(E0[a + 2]);
        const half2_t y0 = ash2(E1[a]), y1 = ash2(E1[a + 2]);
        const half2_t z0 = ash2(E2[a]), z1 = ash2(E2[a + 2]);
        const float t0x = __builtin_amdgcn_fdot2(x1, w01, __builtin_amdgcn_fdot2(x0, w00, 0.0f, false), false);
        const float t1x = __builtin_amdgcn_fdot2(x1, w11, __builtin_amdgcn_fdot2(x0, w10, 0.0f, false), false);
        const float t0y = __builtin_amdgcn_fdot2(y1, w01, __builtin_amdgcn_fdot2(y0, w00, 0.0f, false), false);
        const float t1y = __builtin_amdgcn_fdot2(y1, w11, __builtin_amdgcn_fdot2(y0, w10, 0.0f, false), false);
        const float t0z = __builtin_amdgcn_fdot2(z1, w01, __builtin_amdgcn_fdot2(z0, w00, 0.0f, false), false);
        const float t1z = __builtin_amdgcn_fdot2(z1, w11, __builtin_amdgcn_fdot2(z0, w10, 0.0f, false), false);
        px  = fmaf(bu0[i], t0x, px);  py  = fmaf(bu0[i], t0y, py);  pz  = fmaf(bu0[i], t0z, pz);
        dux = fmaf(bu1[i], t0x, dux); duy = fmaf(bu1[i], t0y, duy); duz = fmaf(bu1[i], t0z, duz);
        dvx = fmaf(bu0[i], t1x, dvx); dvy = fmaf(bu0[i], t1y, dvy); dvz = fmaf(bu0[i], t1z, dvz);
    }

    float nx = duy * dvz - duz * dvy;
    float ny = duz * dvx - dux * dvz;
    float nz = dux * dvy - duy * dvx;
    float n2 = nx * nx + ny * ny + nz * nz;
    const float du2 = dux*dux + duy*duy + duz*duz;
    const float dv2 = dvx*dvx + dvy*dvy + dvz*dvz;

    // Near-parallel du,dv: f16 noise amplified by 1/sin(theta) -> redo in f32.
    if (n2 < 4e-3f * (du2 * dv2)) {
        const float* patch = cp + (size_t)sf * 3072;
        float DUX=0.f, DUY=0.f, DUZ=0.f, DVX=0.f, DVY=0.f, DVZ=0.f;
#pragma unroll
        for (int i = 0; i < 4; ++i) {
            float s0x=0.f, s0y=0.f, s0z=0.f, s1x=0.f, s1y=0.f, s1z=0.f;
#pragma unroll
            for (int j = 0; j < 4; ++j) {
                const float* p = patch + (((bu + i) * 32) + (bv + j)) * 3;
                const float gx = p[0], gy = p[1], gz = p[2];
                s0x = fmaf(gx, bv0[j], s0x); s0y = fmaf(gy, bv0[j], s0y); s0z = fmaf(gz, bv0[j], s0z);
                s1x = fmaf(gx, bv1[j], s1x); s1y = fmaf(gy, bv1[j], s1y); s1z = fmaf(gz, bv1[j], s1z);
            }
            DUX = fmaf(bu1[i], s0x, DUX); DUY = fmaf(bu1[i], s0y, DUY); DUZ = fmaf(bu1[i], s0z, DUZ);
            DVX = fmaf(bu0[i], s1x, DVX); DVY = fmaf(bu0[i], s1y, DVY); DVZ = fmaf(bu0[i], s1z, DVZ);
        }
        nx = DUY * DVZ - DUZ * DVY;
        ny = DUZ * DVX - DUX * DVZ;
        nz = DUX * DVY - DUY * DVX;
        n2 = nx * nx + ny * ny + nz * nz;
    }

    const float inv = __builtin_amdgcn_rsqf(fmaxf(n2, 1e-24f));
    nx *= inv; ny *= inv; nz *= inv;

    // Streamed outputs, never re-read: nontemporal to keep them out of L2.
    f32x4* outv = (f32x4*)out;
    f32x4 pt; pt[0]=px; pt[1]=py; pt[2]=pz; pt[3]=1.0f;
    f32x4 nm; nm[0]=nx; nm[1]=ny; nm[2]=nz; nm[3]=0.0f;
    __builtin_nontemporal_store(pt, &outv[idx]);
    __builtin_nontemporal_store(nm, &outv[(size_t)S_DIM * F_DIM * E_DIM + idx]);
}

extern "C" void kernel_launch(void* const* d_in, const int* in_sizes, int n_in,
                              void* d_out, int out_size, void* d_ws, size_t ws_size,
                              hipStream_t stream) {
    const float* ep = (const float*)d_in[0];
    const float* cp = (const float*)d_in[1];
    float* out = (float*)d_out;

    dim3 grid(E_DIM / 256, S_DIM * F_DIM);
    dim3 block(256);
    hipLaunchKernelGGL(nurbs_eval_kernel, grid, block, 0, stream, ep, cp, out);
}